// Round 1
// baseline (199.321 us; speedup 1.0000x reference)
//
#include <hip/hip_runtime.h>
#include <cstdint>
#include <cstddef>

#define B_ 8
#define N_ 256
#define D_ 128
#define H_ 128
#define K_ 8

// ---------------------------------------------------------------------------
// prep: wd[k,h] = W2[k,h,0]-W2[k,h,1]; consts[k] = {b2diff, w3diff, w3base, _}
// ---------------------------------------------------------------------------
__global__ void prep_kernel(const float* __restrict__ W2, const float* __restrict__ b2,
                            const float* __restrict__ W3, const float* __restrict__ b3,
                            float* __restrict__ wd, float* __restrict__ consts) {
    int t = threadIdx.x;
    for (int idx = t; idx < K_ * H_; idx += 256) {
        wd[idx] = W2[idx * 2] - W2[idx * 2 + 1];
    }
    if (t < K_) {
        consts[t * 4 + 0] = b2[t * 2] - b2[t * 2 + 1];
        consts[t * 4 + 1] = W3[t * 2] - W3[t * 2 + 1];   // W3[k,0,0]-W3[k,1,0]
        consts[t * 4 + 2] = W3[t * 2 + 1] + b3[t];       // W3[k,1,0]+b3[k]
    }
}

// ---------------------------------------------------------------------------
// stage1: G[b,k,i,c] ; c<128 -> hi'[h=c] = E[b,i,:]@W1[k,0:128,c] + b1[k,c]
//                      c>=128 -> hj[h=c-128] = E[b,i,:]@W1[k,128:256,c-128]
// block = (b,k, i-tile of 32), 256 threads, 4x2 micro-tile per thread
// ---------------------------------------------------------------------------
__global__ __launch_bounds__(256) void stage1_kernel(
        const float* __restrict__ E, const float* __restrict__ W1,
        const float* __restrict__ b1, float* __restrict__ G) {
    __shared__ __attribute__((aligned(16))) float Et[D_][36]; // [d][i_local], padded
    __shared__ __attribute__((aligned(16))) float Wt[D_][64]; // [r][c_local]

    const int bid = blockIdx.x;
    const int it  = bid & 7;       // 8 i-tiles of 32
    const int bk  = bid >> 3;      // b*K + k
    const int k   = bk & (K_ - 1);
    const int b   = bk >> 3;
    const int i0  = it * 32;
    const int t   = threadIdx.x;

    // Load E tile transposed: Et[d][il] = E[b][i0+il][d]
    #pragma unroll
    for (int rep = 0; rep < 16; rep++) {
        int idx = rep * 256 + t;
        int d   = idx & 127;
        int il  = idx >> 7;
        Et[d][il] = E[((size_t)(b * N_ + i0 + il)) * D_ + d];
    }

    const int ci = t & 31;   // column pair index (2 columns)
    const int ii = t >> 5;   // i group (4 rows)

    for (int cc = 0; cc < 256; cc += 64) {
        __syncthreads();   // protects Et (first iter) and Wt reuse (later iters)
        const int ro = (cc < 128) ? 0 : 128;
        const int h0 = cc & 127;
        #pragma unroll
        for (int rep = 0; rep < 32; rep++) {
            int idx = rep * 256 + t;
            int r   = idx >> 6;
            int cl  = idx & 63;
            Wt[r][cl] = W1[((size_t)(k * 256 + ro + r)) * H_ + h0 + cl];
        }
        __syncthreads();

        float acc00 = 0.f, acc01 = 0.f, acc10 = 0.f, acc11 = 0.f;
        float acc20 = 0.f, acc21 = 0.f, acc30 = 0.f, acc31 = 0.f;
        #pragma unroll 4
        for (int d = 0; d < 128; d++) {
            float4 e = *(const float4*)&Et[d][ii * 4];
            float2 w = *(const float2*)&Wt[d][ci * 2];
            acc00 = fmaf(e.x, w.x, acc00); acc01 = fmaf(e.x, w.y, acc01);
            acc10 = fmaf(e.y, w.x, acc10); acc11 = fmaf(e.y, w.y, acc11);
            acc20 = fmaf(e.z, w.x, acc20); acc21 = fmaf(e.z, w.y, acc21);
            acc30 = fmaf(e.w, w.x, acc30); acc31 = fmaf(e.w, w.y, acc31);
        }

        const int c = cc + ci * 2;
        float b10 = 0.f, b11 = 0.f;
        if (cc < 128) { b10 = b1[k * H_ + c]; b11 = b1[k * H_ + c + 1]; }

        float a0[4] = {acc00, acc10, acc20, acc30};
        float a1[4] = {acc01, acc11, acc21, acc31};
        #pragma unroll
        for (int a = 0; a < 4; a++) {
            int i = i0 + ii * 4 + a;
            float2 v = make_float2(a0[a] + b10, a1[a] + b11);
            *(float2*)&G[((size_t)bk * N_ + i) * 256 + c] = v;
        }
    }
}

// ---------------------------------------------------------------------------
// stage2: out[b,k,i,j] = entmax-combine( sum_h relu(hi'[i,h]+hj[j,h]) * wd[h] )
// block = (b,k, i-tile of 16); lane = j; hj row in VGPRs; hi/wd scalar loads
// ---------------------------------------------------------------------------
__global__ __launch_bounds__(256) void stage2_kernel(
        const float* __restrict__ G, const float* __restrict__ wd,
        const float* __restrict__ consts, float* __restrict__ out) {
    const int bid = blockIdx.x;
    const int it  = bid & 15;        // 16 i-tiles of 16
    const int bk  = bid >> 4;        // b*K + k
    const int k   = bk & (K_ - 1);
    const int j   = threadIdx.x;     // 0..255

    // Load this lane's hj row (128 floats) into registers
    const float4* hj4 = (const float4*)(G + ((size_t)bk * N_ + j) * 256 + 128);
    float hj[128];
    #pragma unroll
    for (int q = 0; q < 32; q++) {
        float4 v = hj4[q];
        hj[4 * q + 0] = v.x; hj[4 * q + 1] = v.y;
        hj[4 * q + 2] = v.z; hj[4 * q + 3] = v.w;
    }

    const float b2d = consts[k * 4 + 0];
    const float w3d = consts[k * 4 + 1];
    const float w3b = consts[k * 4 + 2];
    const float* __restrict__ wdk    = wd + k * H_;
    const float* __restrict__ hibase = G + ((size_t)bk * N_ + it * 16) * 256;
    float* __restrict__ outbase      = out + ((size_t)bk * N_ + (size_t)it * 16) * N_;

    for (int ii = 0; ii < 16; ii++) {
        const float* __restrict__ hirow = hibase + ii * 256;  // block-uniform
        float acc = b2d;
        #pragma unroll
        for (int h = 0; h < 128; h++) {
            float pre = hirow[h] + hj[h];
            float act = fmaxf(pre, 0.f);
            acc = fmaf(act, wdk[h], acc);
        }
        // entmax15 pair closed form on logit difference
        float tt  = acc * 0.25f;
        float dd  = fabsf(tt);
        float ss  = sqrtf(fmaxf(0.5f - dd * dd, 0.f));
        float p0i = (ss + tt) * (ss + tt);
        float p0  = (dd >= 0.5f) ? (tt > 0.f ? 1.f : 0.f) : p0i;
        float val = fmaf(p0, w3d, w3b);
        int i = it * 16 + ii;
        if (i == j) val = 0.f;   // zero diagonal
        outbase[(size_t)ii * N_ + j] = val;
    }
}

// ---------------------------------------------------------------------------
extern "C" void kernel_launch(void* const* d_in, const int* in_sizes, int n_in,
                              void* d_out, int out_size, void* d_ws, size_t ws_size,
                              hipStream_t stream) {
    (void)in_sizes; (void)n_in; (void)out_size; (void)ws_size;
    const float* E  = (const float*)d_in[0];
    const float* W1 = (const float*)d_in[1];
    const float* b1 = (const float*)d_in[2];
    const float* W2 = (const float*)d_in[3];
    const float* b2 = (const float*)d_in[4];
    const float* W3 = (const float*)d_in[5];
    const float* b3 = (const float*)d_in[6];
    float* out = (float*)d_out;

    char* ws = (char*)d_ws;
    float* wd     = (float*)ws;                 // K*H floats = 4 KB
    float* consts = (float*)(ws + 4096);        // K*4 floats
    float* G      = (float*)(ws + 8192);        // B*K*N*256 floats = 16.78 MB

    prep_kernel<<<1, 256, 0, stream>>>(W2, b2, W3, b3, wd, consts);
    stage1_kernel<<<B_ * K_ * 8, 256, 0, stream>>>(E, W1, b1, G);
    stage2_kernel<<<B_ * K_ * 16, 256, 0, stream>>>(G, wd, consts, out);
}

// Round 2
// 82.508 us; speedup vs baseline: 2.4158x; 2.4158x over previous
//
#include <hip/hip_runtime.h>
#include <cstdint>
#include <cstddef>

#define B_ 8
#define N_ 256
#define D_ 128
#define H_ 128
#define K_ 8

// ---------------------------------------------------------------------------
// prep: wd[k,h] = W2[k,h,0]-W2[k,h,1]; consts[k] = {b2diff, w3diff, w3base, _}
// ---------------------------------------------------------------------------
__global__ void prep_kernel(const float* __restrict__ W2, const float* __restrict__ b2,
                            const float* __restrict__ W3, const float* __restrict__ b3,
                            float* __restrict__ wd, float* __restrict__ consts) {
    int t = threadIdx.x;
    for (int idx = t; idx < K_ * H_; idx += 256) {
        wd[idx] = W2[idx * 2] - W2[idx * 2 + 1];
    }
    if (t < K_) {
        consts[t * 4 + 0] = b2[t * 2] - b2[t * 2 + 1];
        consts[t * 4 + 1] = W3[t * 2] - W3[t * 2 + 1];   // W3[k,0,0]-W3[k,1,0]
        consts[t * 4 + 2] = W3[t * 2 + 1] + b3[t];       // W3[k,1,0]+b3[k]
    }
}

// ---------------------------------------------------------------------------
// stage1: G[b,k,i,c] ; c<128 -> hi'[h=c] = E[b,i,:]@W1[k,0:128,c] + b1[k,c]
//                      c>=128 -> hj[h=c-128] = E[b,i,:]@W1[k,128:256,c-128]
// ---------------------------------------------------------------------------
__global__ __launch_bounds__(256) void stage1_kernel(
        const float* __restrict__ E, const float* __restrict__ W1,
        const float* __restrict__ b1, float* __restrict__ G) {
    __shared__ __attribute__((aligned(16))) float Et[D_][36]; // [d][i_local], padded
    __shared__ __attribute__((aligned(16))) float Wt[D_][64]; // [r][c_local]

    const int bid = blockIdx.x;
    const int it  = bid & 7;       // 8 i-tiles of 32
    const int bk  = bid >> 3;      // b*K + k
    const int k   = bk & (K_ - 1);
    const int b   = bk >> 3;
    const int i0  = it * 32;
    const int t   = threadIdx.x;

    #pragma unroll
    for (int rep = 0; rep < 16; rep++) {
        int idx = rep * 256 + t;
        int d   = idx & 127;
        int il  = idx >> 7;
        Et[d][il] = E[((size_t)(b * N_ + i0 + il)) * D_ + d];
    }

    const int ci = t & 31;   // column pair index (2 columns)
    const int ii = t >> 5;   // i group (4 rows)

    for (int cc = 0; cc < 256; cc += 64) {
        __syncthreads();
        const int ro = (cc < 128) ? 0 : 128;
        const int h0 = cc & 127;
        #pragma unroll
        for (int rep = 0; rep < 32; rep++) {
            int idx = rep * 256 + t;
            int r   = idx >> 6;
            int cl  = idx & 63;
            Wt[r][cl] = W1[((size_t)(k * 256 + ro + r)) * H_ + h0 + cl];
        }
        __syncthreads();

        float acc00 = 0.f, acc01 = 0.f, acc10 = 0.f, acc11 = 0.f;
        float acc20 = 0.f, acc21 = 0.f, acc30 = 0.f, acc31 = 0.f;
        #pragma unroll 4
        for (int d = 0; d < 128; d++) {
            float4 e = *(const float4*)&Et[d][ii * 4];
            float2 w = *(const float2*)&Wt[d][ci * 2];
            acc00 = fmaf(e.x, w.x, acc00); acc01 = fmaf(e.x, w.y, acc01);
            acc10 = fmaf(e.y, w.x, acc10); acc11 = fmaf(e.y, w.y, acc11);
            acc20 = fmaf(e.z, w.x, acc20); acc21 = fmaf(e.z, w.y, acc21);
            acc30 = fmaf(e.w, w.x, acc30); acc31 = fmaf(e.w, w.y, acc31);
        }

        const int c = cc + ci * 2;
        float b10 = 0.f, b11 = 0.f;
        if (cc < 128) { b10 = b1[k * H_ + c]; b11 = b1[k * H_ + c + 1]; }

        float a0[4] = {acc00, acc10, acc20, acc30};
        float a1[4] = {acc01, acc11, acc21, acc31};
        #pragma unroll
        for (int a = 0; a < 4; a++) {
            int i = i0 + ii * 4 + a;
            float2 v = make_float2(a0[a] + b10, a1[a] + b11);
            *(float2*)&G[((size_t)bk * N_ + i) * 256 + c] = v;
        }
    }
}

// ---------------------------------------------------------------------------
// stage2 v2: LDS-tiled 64x64 (i,j) tile, 4x4 micro-tile per thread.
// his[i][h] row-major (pad 132), hjs[h][j] transposed (pad 68), wd in LDS.
// ---------------------------------------------------------------------------
__global__ __launch_bounds__(256, 2) void stage2_kernel(
        const float* __restrict__ G, const float* __restrict__ wd,
        const float* __restrict__ consts, float* __restrict__ out) {
    __shared__ __attribute__((aligned(16))) float his[64][132];
    __shared__ __attribute__((aligned(16))) float hjs[128][68];
    __shared__ float wds[H_];

    const int bid = blockIdx.x;
    const int jt  = bid & 3;
    const int it  = (bid >> 2) & 3;
    const int bk  = bid >> 4;
    const int k   = bk & (K_ - 1);
    const int i0  = it * 64, j0 = jt * 64;
    const int t   = threadIdx.x;

    const float* __restrict__ gb = G + (size_t)bk * N_ * 256;

    // hi tile: coalesced loads, row-major store (write conflicts ~4-way, 8 instrs, negligible)
    #pragma unroll
    for (int rep = 0; rep < 8; rep++) {
        int idx = rep * 256 + t;
        int r = idx >> 5;        // 0..63
        int q = idx & 31;        // float4 within row
        float4 v = *(const float4*)(gb + (size_t)(i0 + r) * 256 + 4 * q);
        *(float4*)&his[r][4 * q] = v;
    }
    // hj tile transposed: lane-fast over rows -> conflict-free scalar writes
    #pragma unroll
    for (int rep = 0; rep < 8; rep++) {
        int idx = rep * 256 + t;
        int r = idx & 63;        // j row
        int q = idx >> 6;        // float4 within row (h/4)
        float4 v = *(const float4*)(gb + (size_t)(j0 + r) * 256 + 128 + 4 * q);
        hjs[4 * q + 0][r] = v.x;
        hjs[4 * q + 1][r] = v.y;
        hjs[4 * q + 2][r] = v.z;
        hjs[4 * q + 3][r] = v.w;
    }
    if (t < H_) wds[t] = wd[k * H_ + t];
    __syncthreads();

    const float b2d = consts[k * 4 + 0];
    const float w3d = consts[k * 4 + 1];
    const float w3b = consts[k * 4 + 2];
    const int tx = t & 15;   // j group: j = j0 + tx*4 + c
    const int ty = t >> 4;   // i group: i = i0 + ty*4 + a

    float acc[4][4];
    #pragma unroll
    for (int a = 0; a < 4; a++)
        #pragma unroll
        for (int c = 0; c < 4; c++) acc[a][c] = b2d;

    #pragma unroll 2
    for (int h = 0; h < 128; h += 4) {
        float4 w4 = *(const float4*)&wds[h];
        float W[4] = {w4.x, w4.y, w4.z, w4.w};
        float A[4][4];
        #pragma unroll
        for (int a = 0; a < 4; a++) {
            float4 v = *(const float4*)&his[ty * 4 + a][h];
            A[a][0] = v.x; A[a][1] = v.y; A[a][2] = v.z; A[a][3] = v.w;
        }
        float Bv[4][4];
        #pragma unroll
        for (int e = 0; e < 4; e++) {
            float4 v = *(const float4*)&hjs[h + e][tx * 4];
            Bv[e][0] = v.x; Bv[e][1] = v.y; Bv[e][2] = v.z; Bv[e][3] = v.w;
        }
        #pragma unroll
        for (int e = 0; e < 4; e++)
            #pragma unroll
            for (int a = 0; a < 4; a++)
                #pragma unroll
                for (int c = 0; c < 4; c++) {
                    float pre = A[a][e] + Bv[e][c];
                    acc[a][c] = fmaf(fmaxf(pre, 0.f), W[e], acc[a][c]);
                }
    }

    // epilogue: entmax15 pair closed form + W3 combine + diagonal zero
    #pragma unroll
    for (int a = 0; a < 4; a++) {
        int i = i0 + ty * 4 + a;
        float vv[4];
        #pragma unroll
        for (int c = 0; c < 4; c++) {
            float av = acc[a][c];
            float tt = av * 0.25f;
            float dd = fabsf(tt);
            float ss = sqrtf(fmaxf(0.5f - dd * dd, 0.f));
            float p0i = (ss + tt) * (ss + tt);
            float p0 = (dd >= 0.5f) ? (tt > 0.f ? 1.f : 0.f) : p0i;
            float val = fmaf(p0, w3d, w3b);
            int j = j0 + tx * 4 + c;
            if (i == j) val = 0.f;
            vv[c] = val;
        }
        *(float4*)(out + ((size_t)bk * N_ + i) * N_ + j0 + tx * 4) =
            make_float4(vv[0], vv[1], vv[2], vv[3]);
    }
}

// ---------------------------------------------------------------------------
extern "C" void kernel_launch(void* const* d_in, const int* in_sizes, int n_in,
                              void* d_out, int out_size, void* d_ws, size_t ws_size,
                              hipStream_t stream) {
    (void)in_sizes; (void)n_in; (void)out_size; (void)ws_size;
    const float* E  = (const float*)d_in[0];
    const float* W1 = (const float*)d_in[1];
    const float* b1 = (const float*)d_in[2];
    const float* W2 = (const float*)d_in[3];
    const float* b2 = (const float*)d_in[4];
    const float* W3 = (const float*)d_in[5];
    const float* b3 = (const float*)d_in[6];
    float* out = (float*)d_out;

    char* ws = (char*)d_ws;
    float* wd     = (float*)ws;                 // K*H floats = 4 KB
    float* consts = (float*)(ws + 4096);        // K*4 floats
    float* G      = (float*)(ws + 8192);        // B*K*N*256 floats = 16.78 MB

    prep_kernel<<<1, 256, 0, stream>>>(W2, b2, W3, b3, wd, consts);
    stage1_kernel<<<B_ * K_ * 8, 256, 0, stream>>>(E, W1, b1, G);
    stage2_kernel<<<B_ * K_ * 16, 256, 0, stream>>>(G, wd, consts, out);
}

// Round 3
// 58.222 us; speedup vs baseline: 3.4234x; 1.4171x over previous
//
#include <hip/hip_runtime.h>
#include <hip/hip_fp16.h>
#include <cstdint>
#include <cstddef>

#define B_ 8
#define N_ 256
#define D_ 128
#define H_ 128
#define K_ 8

typedef _Float16 f16x8 __attribute__((ext_vector_type(8)));
typedef _Float16 f16x2 __attribute__((ext_vector_type(2)));
typedef float    f32x4 __attribute__((ext_vector_type(4)));

static __device__ __forceinline__ f16x2 h2cast(unsigned u) {
    return __builtin_bit_cast(f16x2, u);
}
static __device__ __forceinline__ unsigned packh2(float lo, float hi) {
    unsigned a = __half_as_ushort(__float2half(lo));
    unsigned b = __half_as_ushort(__float2half(hi));
    return a | (b << 16);
}

// ---------------------------------------------------------------------------
// prep_small: wdh[k][hh] = half2(wd[2hh], wd[2hh+1]); consts[k] = {b2d,w3d,w3b}
// ---------------------------------------------------------------------------
__global__ void prep_small(const float* __restrict__ W2, const float* __restrict__ b2,
                           const float* __restrict__ W3, const float* __restrict__ b3,
                           unsigned* __restrict__ wdh, float* __restrict__ consts) {
    int t = threadIdx.x;
    for (int idx = t; idx < K_ * 64; idx += 256) {  // idx = k*64 + hh
        int base = idx * 2;                          // h pair = (2hh, 2hh+1) within k*128
        float w0 = W2[base * 2]     - W2[base * 2 + 1];
        float w1 = W2[base * 2 + 2] - W2[base * 2 + 3];
        wdh[idx] = packh2(w0, w1);
    }
    if (t < K_) {
        consts[t * 4 + 0] = b2[t * 2] - b2[t * 2 + 1];
        consts[t * 4 + 1] = W3[t * 2] - W3[t * 2 + 1];
        consts[t * 4 + 2] = W3[t * 2 + 1] + b3[t];
    }
}

// ---------------------------------------------------------------------------
// prep_eh: E fp32 -> Eh fp16
// ---------------------------------------------------------------------------
__global__ __launch_bounds__(256) void prep_eh(const float* __restrict__ E,
                                               __half* __restrict__ Eh) {
    int idx = (blockIdx.x * 256 + threadIdx.x) * 4;
    float4 v = *(const float4*)&E[idx];
    uint2 o;
    o.x = packh2(v.x, v.y);
    o.y = packh2(v.z, v.w);
    *(uint2*)&Eh[idx] = o;
}

// ---------------------------------------------------------------------------
// prep_wh: Wh[k][c][d] fp16 = W1[k][(c<128? d : 128+d)][c&127]
// block = (k, c-tile of 32); LDS transpose
// ---------------------------------------------------------------------------
__global__ __launch_bounds__(256) void prep_wh(const float* __restrict__ W1,
                                               __half* __restrict__ Wh) {
    __shared__ float Ws[128][33];
    const int bid = blockIdx.x;
    const int ct  = bid & 7;
    const int k   = bid >> 3;
    const int c0  = ct * 32;
    const int ro  = (c0 < 128) ? 0 : 128;
    const int h0  = c0 & 127;
    const int t   = threadIdx.x;

    #pragma unroll
    for (int rep = 0; rep < 16; rep++) {
        int idx = rep * 256 + t;
        int d   = idx >> 5;
        int cl  = idx & 31;
        Ws[d][cl] = W1[((size_t)(k * 256 + ro + d)) * H_ + h0 + cl];
    }
    __syncthreads();

    const int cl = t >> 3;   // 0..31
    const int dg = t & 7;    // 0..7 (16 d each)
    __half tmp[16];
    #pragma unroll
    for (int e = 0; e < 16; e++) tmp[e] = __float2half(Ws[dg * 16 + e][cl]);
    *(float4*)&Wh[((size_t)(k * 256 + c0 + cl)) * D_ + dg * 16]     = *(float4*)&tmp[0];
    *(float4*)&Wh[((size_t)(k * 256 + c0 + cl)) * D_ + dg * 16 + 8] = *(float4*)&tmp[8];
}

// ---------------------------------------------------------------------------
// stage1: fp16 MFMA GEMM. Gh[bk][i][c] = Eh[b,i,:] @ Wh[k,c,:] (+b1 for c<128)
// block = (bk, 64x64 tile), 4 waves of 32x32
// ---------------------------------------------------------------------------
__global__ __launch_bounds__(256) void stage1_kernel(
        const __half* __restrict__ Eh, const __half* __restrict__ Wh,
        const float* __restrict__ b1, __half* __restrict__ Gh) {
    __shared__ __half Es[64 * 136];
    __shared__ __half Ws[64 * 136];

    const int bid = blockIdx.x;
    const int ct  = bid & 3;
    const int it  = (bid >> 2) & 3;
    const int bk  = bid >> 4;
    const int k   = bk & (K_ - 1);
    const int b   = bk >> 3;
    const int i0  = it * 64, c0 = ct * 64;
    const int t   = threadIdx.x;

    #pragma unroll
    for (int rep = 0; rep < 4; rep++) {
        int idx = rep * 256 + t;
        int r = idx >> 4;        // row 0..63
        int q = idx & 15;        // 8-half chunk
        *(float4*)&Es[r * 136 + q * 8] =
            *(const float4*)&Eh[((size_t)(b * N_ + i0 + r)) * D_ + q * 8];
        *(float4*)&Ws[r * 136 + q * 8] =
            *(const float4*)&Wh[((size_t)(k * 256 + c0 + r)) * D_ + q * 8];
    }
    __syncthreads();

    const int wv   = t >> 6;
    const int lane = t & 63;
    const int wr   = wv >> 1, wc = wv & 1;
    const int lr   = lane & 15, lk = lane >> 4;

    f32x4 acc[2][2] = {{{0.f,0.f,0.f,0.f},{0.f,0.f,0.f,0.f}},
                       {{0.f,0.f,0.f,0.f},{0.f,0.f,0.f,0.f}}};
    #pragma unroll
    for (int kk = 0; kk < 4; kk++) {
        f16x8 A[2], Bv[2];
        #pragma unroll
        for (int mi = 0; mi < 2; mi++)
            A[mi] = *(const f16x8*)&Es[(wr * 32 + mi * 16 + lr) * 136 + kk * 32 + lk * 8];
        #pragma unroll
        for (int ni = 0; ni < 2; ni++)
            Bv[ni] = *(const f16x8*)&Ws[(wc * 32 + ni * 16 + lr) * 136 + kk * 32 + lk * 8];
        #pragma unroll
        for (int mi = 0; mi < 2; mi++)
            #pragma unroll
            for (int ni = 0; ni < 2; ni++)
                acc[mi][ni] = __builtin_amdgcn_mfma_f32_16x16x32_f16(
                    A[mi], Bv[ni], acc[mi][ni], 0, 0, 0);
    }

    #pragma unroll
    for (int ni = 0; ni < 2; ni++) {
        int col = c0 + wc * 32 + ni * 16 + lr;
        float bias = (col < 128) ? b1[k * H_ + col] : 0.f;
        #pragma unroll
        for (int mi = 0; mi < 2; mi++) {
            int rbase = i0 + wr * 32 + mi * 16 + lk * 4;
            #pragma unroll
            for (int r = 0; r < 4; r++) {
                Gh[((size_t)(bk * N_ + rbase + r)) * 256 + col] =
                    __float2half(acc[mi][ni][r] + bias);
            }
        }
    }
}

// ---------------------------------------------------------------------------
// stage2: fp16-packed pairwise kernel. 64x64 tile, 4x4 micro (interleaved),
// inner: pk_add_f16 + pk_max_f16 + v_dot2_f32_f16 (fp32 acc)
// ---------------------------------------------------------------------------
__global__ __launch_bounds__(256) void stage2_kernel(
        const __half* __restrict__ Gh, const unsigned* __restrict__ wdh,
        const float* __restrict__ consts, float* __restrict__ out) {
    __shared__ __half his[64 * 136];
    __shared__ __half hjs[64 * 136];

    const int bid = blockIdx.x;
    const int jt  = bid & 3;
    const int it  = (bid >> 2) & 3;
    const int bk  = bid >> 4;
    const int k   = bk & (K_ - 1);
    const int i0  = it * 64, j0 = jt * 64;
    const int t   = threadIdx.x;

    const __half* __restrict__ gb = Gh + (size_t)bk * N_ * 256;

    #pragma unroll
    for (int rep = 0; rep < 4; rep++) {
        int idx = rep * 256 + t;
        int r = idx >> 4;
        int q = idx & 15;
        *(float4*)&his[r * 136 + q * 8] =
            *(const float4*)&gb[(size_t)(i0 + r) * 256 + q * 8];
        *(float4*)&hjs[r * 136 + q * 8] =
            *(const float4*)&gb[(size_t)(j0 + r) * 256 + 128 + q * 8];
    }
    __syncthreads();

    const float b2d = consts[k * 4 + 0];
    const float w3d = consts[k * 4 + 1];
    const float w3b = consts[k * 4 + 2];
    const int tx = t & 15;   // j = j0 + tx + 16c
    const int ty = t >> 4;   // i = i0 + ty + 16a

    float acc[4][4];
    #pragma unroll
    for (int a = 0; a < 4; a++)
        #pragma unroll
        for (int c = 0; c < 4; c++) acc[a][c] = b2d;

    const unsigned* __restrict__ wp = wdh + k * 64;
    const f16x2 zz = {(_Float16)0, (_Float16)0};

    #pragma unroll 2
    for (int hq = 0; hq < 16; hq++) {   // 8 h per iter
        unsigned Wv[4];
        *(uint4*)&Wv[0] = *(const uint4*)&wp[hq * 4];
        unsigned Aa[4][4], Bb[4][4];
        #pragma unroll
        for (int a = 0; a < 4; a++)
            *(uint4*)&Aa[a][0] = *(const uint4*)&his[(ty + 16 * a) * 136 + hq * 8];
        #pragma unroll
        for (int c = 0; c < 4; c++)
            *(uint4*)&Bb[c][0] = *(const uint4*)&hjs[(tx + 16 * c) * 136 + hq * 8];

        #pragma unroll
        for (int e = 0; e < 4; e++) {
            f16x2 w2 = h2cast(Wv[e]);
            #pragma unroll
            for (int a = 0; a < 4; a++) {
                f16x2 av = h2cast(Aa[a][e]);
                #pragma unroll
                for (int c = 0; c < 4; c++) {
                    f16x2 pre = av + h2cast(Bb[c][e]);
                    f16x2 act = __builtin_elementwise_max(pre, zz);
                    acc[a][c] = __builtin_amdgcn_fdot2(act, w2, acc[a][c], false);
                }
            }
        }
    }

    #pragma unroll
    for (int a = 0; a < 4; a++) {
        int i = i0 + ty + 16 * a;
        #pragma unroll
        for (int c = 0; c < 4; c++) {
            float av = acc[a][c];
            float tt = av * 0.25f;
            float dd = fabsf(tt);
            float ss = sqrtf(fmaxf(0.5f - dd * dd, 0.f));
            float p0i = (ss + tt) * (ss + tt);
            float p0 = (dd >= 0.5f) ? (tt > 0.f ? 1.f : 0.f) : p0i;
            float val = fmaf(p0, w3d, w3b);
            int j = j0 + tx + 16 * c;
            if (i == j) val = 0.f;
            out[((size_t)bk * N_ + i) * N_ + j] = val;
        }
    }
}

// ---------------------------------------------------------------------------
extern "C" void kernel_launch(void* const* d_in, const int* in_sizes, int n_in,
                              void* d_out, int out_size, void* d_ws, size_t ws_size,
                              hipStream_t stream) {
    (void)in_sizes; (void)n_in; (void)out_size; (void)ws_size;
    const float* E  = (const float*)d_in[0];
    const float* W1 = (const float*)d_in[1];
    const float* b1 = (const float*)d_in[2];
    const float* W2 = (const float*)d_in[3];
    const float* b2 = (const float*)d_in[4];
    const float* W3 = (const float*)d_in[5];
    const float* b3 = (const float*)d_in[6];
    float* out = (float*)d_out;

    char* ws = (char*)d_ws;
    unsigned* wdh   = (unsigned*)ws;                     // K*64 half2 = 2 KB
    float*    consts= (float*)(ws + 4096);               // K*4 floats
    __half*   Eh    = (__half*)(ws + 8192);              // 512 KB
    __half*   Wh    = (__half*)(ws + 8192 + 524288);     // 512 KB
    __half*   Gh    = (__half*)(ws + 8192 + 1048576);    // 8.39 MB

    prep_small<<<1, 256, 0, stream>>>(W2, b2, W3, b3, wdh, consts);
    prep_eh<<<B_ * N_ * D_ / 1024, 256, 0, stream>>>(E, Eh);
    prep_wh<<<K_ * 8, 256, 0, stream>>>(W1, Wh);
    stage1_kernel<<<B_ * K_ * 16, 256, 0, stream>>>(Eh, Wh, b1, Gh);
    stage2_kernel<<<B_ * K_ * 16, 256, 0, stream>>>(Gh, wdh, consts, out);
}

// Round 4
// 56.161 us; speedup vs baseline: 3.5491x; 1.0367x over previous
//
#include <hip/hip_runtime.h>
#include <hip/hip_fp16.h>
#include <cstdint>
#include <cstddef>

#define B_ 8
#define N_ 256
#define D_ 128
#define H_ 128
#define K_ 8

typedef _Float16 f16x8 __attribute__((ext_vector_type(8)));
typedef _Float16 f16x2 __attribute__((ext_vector_type(2)));
typedef float    f32x4 __attribute__((ext_vector_type(4)));

static __device__ __forceinline__ f16x2 h2cast(unsigned u) {
    return __builtin_bit_cast(f16x2, u);
}
static __device__ __forceinline__ unsigned packh2(float lo, float hi) {
    unsigned a = __half_as_ushort(__float2half(lo));
    unsigned b = __half_as_ushort(__float2half(hi));
    return a | (b << 16);
}

// ---------------------------------------------------------------------------
// prep_all: one kernel, three jobs selected by blockIdx.x
//   [0,256)   : Eh = fp16(E)
//   [256,320) : Wh[k][c][d] = fp16( W1[k][(c<128? d : 128+d)][c&127] )
//   320       : wdh (half2 of W2 col-diff) + consts
// ---------------------------------------------------------------------------
__global__ __launch_bounds__(256) void prep_all(
        const float* __restrict__ E, const float* __restrict__ W1,
        const float* __restrict__ W2, const float* __restrict__ b2,
        const float* __restrict__ W3, const float* __restrict__ b3,
        __half* __restrict__ Eh, __half* __restrict__ Wh,
        unsigned* __restrict__ wdh, float* __restrict__ consts) {
    __shared__ float Ws[128][33];
    const int bid = blockIdx.x;
    const int t   = threadIdx.x;

    if (bid < 256) {
        int idx = (bid * 256 + t) * 4;
        float4 v = *(const float4*)&E[idx];
        uint2 o;
        o.x = packh2(v.x, v.y);
        o.y = packh2(v.z, v.w);
        *(uint2*)&Eh[idx] = o;
    } else if (bid < 320) {
        const int kb = bid - 256;
        const int ct = kb & 7;
        const int k  = kb >> 3;
        const int c0 = ct * 32;
        const int ro = (c0 < 128) ? 0 : 128;
        const int h0 = c0 & 127;
        #pragma unroll
        for (int rep = 0; rep < 16; rep++) {
            int idx = rep * 256 + t;
            int d   = idx >> 5;
            int cl  = idx & 31;
            Ws[d][cl] = W1[((size_t)(k * 256 + ro + d)) * H_ + h0 + cl];
        }
        __syncthreads();
        const int cl = t >> 3;   // 0..31
        const int dg = t & 7;    // 0..7 (16 d each)
        __half tmp[16];
        #pragma unroll
        for (int e = 0; e < 16; e++) tmp[e] = __float2half(Ws[dg * 16 + e][cl]);
        *(float4*)&Wh[((size_t)(k * 256 + c0 + cl)) * D_ + dg * 16]     = *(float4*)&tmp[0];
        *(float4*)&Wh[((size_t)(k * 256 + c0 + cl)) * D_ + dg * 16 + 8] = *(float4*)&tmp[8];
    } else {
        for (int idx = t; idx < K_ * 64; idx += 256) {  // idx = k*64 + hh
            int base = idx * 2;
            float w0 = W2[base * 2]     - W2[base * 2 + 1];
            float w1 = W2[base * 2 + 2] - W2[base * 2 + 3];
            wdh[idx] = packh2(w0, w1);
        }
        if (t < K_) {
            consts[t * 4 + 0] = b2[t * 2] - b2[t * 2 + 1];
            consts[t * 4 + 1] = W3[t * 2] - W3[t * 2 + 1];
            consts[t * 4 + 2] = W3[t * 2 + 1] + b3[t];
        }
    }
}

// ---------------------------------------------------------------------------
// fused: per block (bk, 64x64 i/j tile):
//   stage A (MFMA): waves 0,1 -> his[64][128] = Eh[i-tile] @ Wh[:,0:128] + b1
//                   waves 2,3 -> hjs[64][128] = Eh[j-tile] @ Wh[:,128:256]
//   stage B (VALU): acc += dot2(pk_max(pk_add(hi,hj),0), wd); entmax epilogue
// ---------------------------------------------------------------------------
__global__ __launch_bounds__(256, 4) void fused_kernel(
        const __half* __restrict__ Eh, const __half* __restrict__ Wh,
        const float* __restrict__ b1, const unsigned* __restrict__ wdh,
        const float* __restrict__ consts, float* __restrict__ out) {
    __shared__ __half his[64 * 136];
    __shared__ __half hjs[64 * 136];

    const int bid = blockIdx.x;
    const int jt  = bid & 3;
    const int it  = (bid >> 2) & 3;
    const int bk  = bid >> 4;
    const int k   = bk & (K_ - 1);
    const int b   = bk >> 3;
    const int i0  = it * 64, j0 = jt * 64;
    const int t   = threadIdx.x;
    const int wv   = t >> 6;
    const int lane = t & 63;
    const int lr   = lane & 15, lk = lane >> 4;

    // ---- stage A: produce his / hjs via MFMA ----
    {
        const bool isJ   = (wv >= 2);
        const int  half32 = wv & 1;
        const int  rowbase = (isJ ? j0 : i0) + half32 * 32;
        const int  cbase   = isJ ? 128 : 0;
        __half* __restrict__ dst = isJ ? hjs : his;

        f16x8 A[2][4];
        #pragma unroll
        for (int mi = 0; mi < 2; mi++)
            #pragma unroll
            for (int kk = 0; kk < 4; kk++)
                A[mi][kk] = *(const f16x8*)&Eh[
                    ((size_t)(b * N_ + rowbase + mi * 16 + lr)) * D_ + kk * 32 + lk * 8];

        #pragma unroll
        for (int nc = 0; nc < 8; nc++) {
            f16x8 Bf[4];
            #pragma unroll
            for (int kk = 0; kk < 4; kk++)
                Bf[kk] = *(const f16x8*)&Wh[
                    ((size_t)(k * 256 + cbase + nc * 16 + lr)) * D_ + kk * 32 + lk * 8];
            const int hcol = nc * 16 + lr;
            const float bias = isJ ? 0.f : b1[k * H_ + hcol];
            #pragma unroll
            for (int mi = 0; mi < 2; mi++) {
                f32x4 acc = {0.f, 0.f, 0.f, 0.f};
                #pragma unroll
                for (int kk = 0; kk < 4; kk++)
                    acc = __builtin_amdgcn_mfma_f32_16x16x32_f16(A[mi][kk], Bf[kk], acc, 0, 0, 0);
                const int lrow = half32 * 32 + mi * 16 + lk * 4;
                #pragma unroll
                for (int q = 0; q < 4; q++)
                    dst[(lrow + q) * 136 + hcol] = __float2half(acc[q] + bias);
            }
        }
    }
    __syncthreads();

    // ---- stage B: pairwise fp16 dot with relu ----
    const float b2d = consts[k * 4 + 0];
    const float w3d = consts[k * 4 + 1];
    const float w3b = consts[k * 4 + 2];
    const int tx = t & 15;   // j = j0 + tx + 16c
    const int ty = t >> 4;   // i = i0 + ty + 16a

    float acc[4][4];
    #pragma unroll
    for (int a = 0; a < 4; a++)
        #pragma unroll
        for (int c = 0; c < 4; c++) acc[a][c] = b2d;

    const unsigned* __restrict__ wp = wdh + k * 64;
    const f16x2 zz = {(_Float16)0, (_Float16)0};

    #pragma unroll 2
    for (int hq = 0; hq < 16; hq++) {   // 8 h per iter
        unsigned Wv[4];
        *(uint4*)&Wv[0] = *(const uint4*)&wp[hq * 4];
        unsigned Aa[4][4], Bb[4][4];
        #pragma unroll
        for (int a = 0; a < 4; a++)
            *(uint4*)&Aa[a][0] = *(const uint4*)&his[(ty + 16 * a) * 136 + hq * 8];
        #pragma unroll
        for (int c = 0; c < 4; c++)
            *(uint4*)&Bb[c][0] = *(const uint4*)&hjs[(tx + 16 * c) * 136 + hq * 8];

        #pragma unroll
        for (int e = 0; e < 4; e++) {
            f16x2 w2 = h2cast(Wv[e]);
            #pragma unroll
            for (int a = 0; a < 4; a++) {
                f16x2 av = h2cast(Aa[a][e]);
                #pragma unroll
                for (int c = 0; c < 4; c++) {
                    f16x2 pre = av + h2cast(Bb[c][e]);
                    f16x2 act = __builtin_elementwise_max(pre, zz);
                    acc[a][c] = __builtin_amdgcn_fdot2(act, w2, acc[a][c], false);
                }
            }
        }
    }

    #pragma unroll
    for (int a = 0; a < 4; a++) {
        int i = i0 + ty + 16 * a;
        #pragma unroll
        for (int c = 0; c < 4; c++) {
            float av = acc[a][c];
            float tt = av * 0.25f;
            float dd = fabsf(tt);
            float ss = sqrtf(fmaxf(0.5f - dd * dd, 0.f));
            float p0i = (ss + tt) * (ss + tt);
            float p0 = (dd >= 0.5f) ? (tt > 0.f ? 1.f : 0.f) : p0i;
            float val = fmaf(p0, w3d, w3b);
            int j = j0 + tx + 16 * c;
            if (i == j) val = 0.f;
            out[((size_t)bk * N_ + i) * N_ + j] = val;
        }
    }
}

// ---------------------------------------------------------------------------
extern "C" void kernel_launch(void* const* d_in, const int* in_sizes, int n_in,
                              void* d_out, int out_size, void* d_ws, size_t ws_size,
                              hipStream_t stream) {
    (void)in_sizes; (void)n_in; (void)out_size; (void)ws_size;
    const float* E  = (const float*)d_in[0];
    const float* W1 = (const float*)d_in[1];
    const float* b1 = (const float*)d_in[2];
    const float* W2 = (const float*)d_in[3];
    const float* b2 = (const float*)d_in[4];
    const float* W3 = (const float*)d_in[5];
    const float* b3 = (const float*)d_in[6];
    float* out = (float*)d_out;

    char* ws = (char*)d_ws;
    unsigned* wdh    = (unsigned*)ws;                    // K*64 half2 = 2 KB
    float*    consts = (float*)(ws + 4096);              // K*4 floats
    __half*   Eh     = (__half*)(ws + 8192);             // 512 KB
    __half*   Wh     = (__half*)(ws + 8192 + 524288);    // 512 KB

    prep_all<<<321, 256, 0, stream>>>(E, W1, W2, b2, W3, b3, Eh, Wh, wdh, consts);
    fused_kernel<<<B_ * K_ * 16, 256, 0, stream>>>(Eh, Wh, b1, wdh, consts, out);
}